// Round 13
// baseline (142.374 us; speedup 1.0000x reference)
//
#include <hip/hip_runtime.h>
#include <hip/hip_cooperative_groups.h>

namespace cg = cooperative_groups;

#define NPIX 6400

typedef float f4 __attribute__((ext_vector_type(4)));
typedef float f16v __attribute__((ext_vector_type(16)));
typedef short bf16x8 __attribute__((ext_vector_type(8)));
typedef unsigned int u4 __attribute__((ext_vector_type(4)));
typedef unsigned int u2 __attribute__((ext_vector_type(2)));
typedef _Float16 h8 __attribute__((ext_vector_type(8)));
typedef _Float16 h4 __attribute__((ext_vector_type(4)));
typedef unsigned short u16;
typedef unsigned int u32;

__device__ __forceinline__ u32 pk_bf16(float lo, float hi){
  u32 r;
  asm("v_cvt_pk_bf16_f32 %0, %1, %2" : "=v"(r) : "v"(lo), "v"(hi));
  return r;
}
__device__ __forceinline__ float bf2f(u16 h){
  union { u32 u; float f; } v; v.u = (u32)h << 16; return v.f;
}
__device__ __forceinline__ float exp2_hw(float x){ return __builtin_amdgcn_exp2f(x); }

// ---------------- K1: FUSED proj GEMM + grid-sync + BN affine/ReLU/bf16 stores ----------------
// coop grid 150 x 512: proj = bid/50, pt = bid%50 (128-px tile). acc stays in registers
// across the grid sync — no Y buffer at all.
__global__ __launch_bounds__(512, 1) void k_projnorm(
    const float* __restrict__ xq, const float* __restrict__ xk, const float* __restrict__ xv,
    const float* __restrict__ wq, const float* __restrict__ bq,
    const float* __restrict__ wk, const float* __restrict__ bk,
    const float* __restrict__ wv, const float* __restrict__ bv,
    const float* __restrict__ gq, const float* __restrict__ beq,
    const float* __restrict__ gk, const float* __restrict__ bek,
    const float* __restrict__ gv, const float* __restrict__ bev,
    u16* __restrict__ q2, u16* __restrict__ k2, u16* __restrict__ v2t,
    float* __restrict__ rowsumq, float* __restrict__ psum, float* __restrict__ psq)
{
  __shared__ __align__(16) float wT[64][132];
  __shared__ __align__(16) float xt[64][132];
  __shared__ __align__(16) float red[2][16][128];
  __shared__ float sc[128], sh[128];
  const int bid = blockIdx.x;
  const int proj = bid / 50, pt = bid % 50;
  const float* x = (proj == 0) ? xq : ((proj == 1) ? xk : xv);
  const float* w = (proj == 0) ? wq : ((proj == 1) ? wk : wv);
  const float* b = (proj == 0) ? bq : ((proj == 1) ? bk : bv);
  const int t = threadIdx.x;
  const int o0 = (t & 31) * 4, p0 = (t >> 5) * 8;
  float acc[4][8];
  #pragma unroll
  for (int i = 0; i < 4; ++i)
    #pragma unroll
    for (int j = 0; j < 8; ++j) acc[i][j] = 0.f;
  for (int cc = 0; cc < 2; ++cc){
    __syncthreads();
    for (int idx = t; idx < 2048; idx += 512){
      int o = idx >> 4, c4 = (idx & 15) * 4;
      f4 wv4 = *(const f4*)&w[o * 128 + cc * 64 + c4];
      wT[c4 + 0][o] = wv4[0]; wT[c4 + 1][o] = wv4[1];
      wT[c4 + 2][o] = wv4[2]; wT[c4 + 3][o] = wv4[3];
    }
    for (int idx = t; idx < 2048; idx += 512){
      int c = idx >> 5, p4 = (idx & 31) * 4;
      *(f4*)&xt[c][p4] = *(const f4*)&x[(cc * 64 + c) * NPIX + pt * 128 + p4];
    }
    __syncthreads();
    for (int c = 0; c < 64; ++c){
      f4 w4 = *(const f4*)&wT[c][o0];
      f4 x0 = *(const f4*)&xt[c][p0];
      f4 x1 = *(const f4*)&xt[c][p0 + 4];
      #pragma unroll
      for (int i = 0; i < 4; ++i){
        float wi = w4[i];
        #pragma unroll
        for (int j = 0; j < 4; ++j){ acc[i][j] += wi * x0[j]; acc[i][4 + j] += wi * x1[j]; }
      }
    }
  }
  f4 b4 = *(const f4*)&b[o0];
  #pragma unroll
  for (int i = 0; i < 4; ++i)
    #pragma unroll
    for (int j = 0; j < 8; ++j) acc[i][j] += b4[i];
  // BN partial stats (per-channel, this block's 128 px)
  #pragma unroll
  for (int i = 0; i < 4; ++i){
    float s = 0.f, q = 0.f;
    #pragma unroll
    for (int j = 0; j < 8; ++j){ s += acc[i][j]; q += acc[i][j] * acc[i][j]; }
    red[0][t >> 5][o0 + i] = s;
    red[1][t >> 5][o0 + i] = q;
  }
  __syncthreads();
  if (t < 128){
    float s = 0.f, q = 0.f;
    #pragma unroll
    for (int g = 0; g < 16; ++g){ s += red[0][g][t]; q += red[1][g][t]; }
    psum[(proj * 50 + pt) * 128 + t] = s;
    psq [(proj * 50 + pt) * 128 + t] = q;
  }

  cg::this_grid().sync();     // stats from all 50 tiles of this proj now visible

  if (t < 128){
    float s = 0.f, q = 0.f;
    for (int i = 0; i < 50; ++i){
      s += psum[(proj * 50 + i) * 128 + t];
      q += psq [(proj * 50 + i) * 128 + t];
    }
    float mean = s * (1.f / NPIX);
    float var  = q * (1.f / NPIX) - mean * mean;
    const float* g  = (proj == 0) ? gq : ((proj == 1) ? gk : gv);
    const float* be = (proj == 0) ? beq : ((proj == 1) ? bek : bev);
    float scale = g[t] * rsqrtf(var + 1e-5f);
    sc[t] = scale; sh[t] = be[t] - mean * scale;
  }
  __syncthreads();
  f4 scv = *(const f4*)&sc[o0];
  f4 shv = *(const f4*)&sh[o0];
  float vv[4][8];
  #pragma unroll
  for (int i = 0; i < 4; ++i)
    #pragma unroll
    for (int j = 0; j < 8; ++j)
      vv[i][j] = fmaxf(acc[i][j] * scv[i] + shv[i], 0.f);
  const float qs_l2 = 0.12751700f;   // 1/sqrt(128)/ln2 folded into Q
  if (proj < 2){
    const float os = (proj == 0) ? qs_l2 : 1.f;
    u16* dst = (proj == 0) ? q2 : k2;
    #pragma unroll
    for (int j = 0; j < 8; ++j){
      u2 v;
      v[0] = pk_bf16(vv[0][j] * os, vv[1][j] * os);
      v[1] = pk_bf16(vv[2][j] * os, vv[3][j] * os);
      *(u2*)&dst[(size_t)(pt * 128 + p0 + j) * 128 + o0] = v;
    }
    if (proj == 0){
      float rs[8];
      #pragma unroll
      for (int j = 0; j < 8; ++j) rs[j] = vv[0][j] + vv[1][j] + vv[2][j] + vv[3][j];
      #pragma unroll
      for (int msk = 1; msk < 32; msk <<= 1)
        #pragma unroll
        for (int j = 0; j < 8; ++j) rs[j] += __shfl_xor(rs[j], msk);
      if ((t & 31) == 0)
        #pragma unroll
        for (int j = 0; j < 8; ++j)
          rowsumq[pt * 128 + p0 + j] = rs[j] * 1.4426950408889634f;   // 1/ln2 folded
    }
  } else {
    #pragma unroll
    for (int i = 0; i < 4; ++i){
      u4 v;
      #pragma unroll
      for (int jj = 0; jj < 4; ++jj)
        v[jj] = pk_bf16(vv[i][jj * 2], vv[i][jj * 2 + 1]);
      *(u4*)&v2t[(size_t)(o0 + i) * NPIX + pt * 128 + p0] = v;
    }
  }
}

// ---------------- K2: flash attention, 512 thr, LDS dbuf, 4-way QK ILP, NKT compile-time ----
template<int NKT>
__global__ __launch_bounds__(512, 2) void k_flash(
    const u16* __restrict__ q2, const u16* __restrict__ k2, const u16* __restrict__ v2t,
    const float* __restrict__ rowsumq, const float* __restrict__ pos,
    _Float16* __restrict__ Opart, float* __restrict__ Mout, float* __restrict__ Lout,
    int js)
{
  __shared__ __align__(16) u16 Kt[2][64 * 128];
  __shared__ __align__(16) u16 Vt[2][128 * 64];
  __shared__ __align__(16) float posT[2][64];
  const int bid = blockIdx.x;
  const int qb = bid / js, jsi = bid % js;
  const int kt0 = jsi * NKT;
  const int tid = threadIdx.x;
  const int ln = tid & 63, wid = tid >> 6;
  const int lo = ln & 31, hi = ln >> 5;
  const int qrow = qb * 256 + wid * 32 + lo;

  const int kc_j = tid >> 4, kc_c8 = tid & 15;
  const int vc_d = tid >> 3, vc_c8 = tid & 7;
  bf16x8 kreg0, kreg1, vreg0, vreg1; float posr = 0.f;
  auto stage_load = [&](int j0){
    kreg0 = *(const bf16x8*)(k2 + (size_t)(j0 + kc_j) * 128 + kc_c8 * 8);
    kreg1 = *(const bf16x8*)(k2 + (size_t)(j0 + kc_j + 32) * 128 + kc_c8 * 8);
    vreg0 = *(const bf16x8*)(v2t + (size_t)vc_d * NPIX + j0 + vc_c8 * 8);
    vreg1 = *(const bf16x8*)(v2t + (size_t)(vc_d + 64) * NPIX + j0 + vc_c8 * 8);
    if (tid < 64) posr = pos[j0 + tid];
  };
  auto stage_write = [&](int b){
    char* kb = (char*)&Kt[b][0];
    char* vb = (char*)&Vt[b][0];
    *(bf16x8*)(kb + kc_j * 256 + ((kc_c8 * 16) ^ ((kc_j & 15) << 4))) = kreg0;
    *(bf16x8*)(kb + (kc_j + 32) * 256 + ((kc_c8 * 16) ^ (((kc_j + 32) & 15) << 4))) = kreg1;
    *(bf16x8*)(vb + vc_d * 128 + ((vc_c8 * 16) ^ ((vc_d & 7) << 4))) = vreg0;
    *(bf16x8*)(vb + (vc_d + 64) * 128 + ((vc_c8 * 16) ^ (((vc_d + 64) & 7) << 4))) = vreg1;
    if (tid < 64) posT[b][tid] = posr;
  };

  bf16x8 qf[8];
  const u16* qp = q2 + (size_t)qrow * 128 + hi * 8;
  #pragma unroll
  for (int kk = 0; kk < 8; ++kk) qf[kk] = *(const bf16x8*)(qp + kk * 16);
  const float rsq_l2 = rowsumq[qrow];          // pre-multiplied by 1/ln2
  f16v accO[4];
  #pragma unroll
  for (int c = 0; c < 4; ++c)
    #pragma unroll
    for (int r = 0; r < 16; ++r) accO[c][r] = 0.f;
  float m = -1e30f, l = 0.f;

  stage_load(kt0 * 64);
  stage_write(0);
  __syncthreads();
  int cur = 0;

  #pragma unroll 2
  for (int kt = 0; kt < NKT; ++kt){
    const bool more = (kt + 1 < NKT);
    if (more) stage_load((kt0 + kt + 1) * 64);

    f16v aS0a, aS0b, aS1a, aS1b;
    #pragma unroll
    for (int r = 0; r < 16; ++r){ aS0a[r] = 0.f; aS0b[r] = 0.f; aS1a[r] = 0.f; aS1b[r] = 0.f; }
    {
      const char* kb0 = (const char*)&Kt[cur][0] + lo * 256;
      const char* kb1 = (const char*)&Kt[cur][0] + (32 + lo) * 256;
      const int sw = (lo & 15) << 4;
      #pragma unroll
      for (int kk = 0; kk < 4; ++kk){
        int boA = (kk * 32 + hi * 16) ^ sw;
        int boB = ((kk + 4) * 32 + hi * 16) ^ sw;
        bf16x8 kf0a = *(const bf16x8*)(kb0 + boA);
        bf16x8 kf1a = *(const bf16x8*)(kb1 + boA);
        bf16x8 kf0b = *(const bf16x8*)(kb0 + boB);
        bf16x8 kf1b = *(const bf16x8*)(kb1 + boB);
        aS0a = __builtin_amdgcn_mfma_f32_32x32x16_bf16(kf0a, qf[kk], aS0a, 0, 0, 0);
        aS1a = __builtin_amdgcn_mfma_f32_32x32x16_bf16(kf1a, qf[kk], aS1a, 0, 0, 0);
        aS0b = __builtin_amdgcn_mfma_f32_32x32x16_bf16(kf0b, qf[kk + 4], aS0b, 0, 0, 0);
        aS1b = __builtin_amdgcn_mfma_f32_32x32x16_bf16(kf1b, qf[kk + 4], aS1b, 0, 0, 0);
      }
    }
    float pv[32];
    float mx = -1e30f;
    #pragma unroll
    for (int jsb = 0; jsb < 2; ++jsb){
      #pragma unroll
      for (int g = 0; g < 4; ++g){
        f4 p4 = *(const f4*)&posT[cur][jsb * 32 + g * 8 + hi * 4];
        #pragma unroll
        for (int e = 0; e < 4; ++e){
          float sraw = jsb ? (aS1a[g * 4 + e] + aS1b[g * 4 + e])
                           : (aS0a[g * 4 + e] + aS0b[g * 4 + e]);
          float sv = sraw + rsq_l2 * p4[e];     // log2-domain (Q pre-scaled)
          pv[jsb * 16 + g * 4 + e] = sv;
          mx = fmaxf(mx, sv);
        }
      }
    }
    mx = fmaxf(mx, __shfl_xor(mx, 32));
    if (!__all(mx - m <= 11.5f)){
      float mnew = fmaxf(m, mx);
      float corr = exp2_hw(m - mnew);
      m = mnew;
      l *= corr;
      #pragma unroll
      for (int c = 0; c < 4; ++c)
        #pragma unroll
        for (int r = 0; r < 16; ++r) accO[c][r] *= corr;
    }
    float ls = 0.f;
    u32 pk[16];
    #pragma unroll
    for (int i = 0; i < 16; ++i){
      float e0 = exp2_hw(pv[2 * i]     - m);
      float e1 = exp2_hw(pv[2 * i + 1] - m);
      ls += e0 + e1;
      pk[i] = pk_bf16(e0, e1);
    }
    ls += __shfl_xor(ls, 32);
    l += ls;

    if (more) stage_write(cur ^ 1);

    #pragma unroll
    for (int w = 0; w < 4; ++w){
      const int b0 = (w >> 1) * 8 + (w & 1) * 4;
      u32 s0 = __shfl_xor(pk[b0], 32);
      u32 s1 = __shfl_xor(pk[b0 + 1], 32);
      u32 s2 = __shfl_xor(pk[b0 + 2], 32);
      u32 s3 = __shfl_xor(pk[b0 + 3], 32);
      union { bf16x8 v; u32 u[4]; } pf;
      pf.u[0] = hi ? s2 : pk[b0];
      pf.u[1] = hi ? s3 : pk[b0 + 1];
      pf.u[2] = hi ? pk[b0 + 2] : s0;
      pf.u[3] = hi ? pk[b0 + 3] : s1;
      #pragma unroll
      for (int c = 0; c < 4; ++c){
        int d = c * 32 + lo;
        bf16x8 vf = *(const bf16x8*)((const char*)&Vt[cur][0] + d * 128 + ((w * 32 + hi * 16) ^ ((d & 7) << 4)));
        accO[c] = __builtin_amdgcn_mfma_f32_32x32x16_bf16(vf, pf.v, accO[c], 0, 0, 0);
      }
    }
    if (more) __syncthreads();
    cur ^= 1;
  }
  if (hi == 0){
    Mout[jsi * NPIX + qrow] = m;
    Lout[jsi * NPIX + qrow] = l;
  }
  const float linv = 1.f / l;
  _Float16* Ob = Opart + ((size_t)jsi * NPIX + qrow) * 128;
  #pragma unroll
  for (int c = 0; c < 4; ++c){
    #pragma unroll
    for (int g = 0; g < 4; ++g){
      h4 hv;
      #pragma unroll
      for (int e = 0; e < 4; ++e) hv[e] = (_Float16)(accO[c][g * 4 + e] * linv);
      *(h4*)&Ob[c * 32 + g * 8 + hi * 4] = hv;
    }
  }
}

// ---------------- K3: FUSED combine + GEMM1 + BN2 + GEMM2 (coop, 200 x 256) ----------------
// Phase1: wo1->wl, combine->Ct, GEMM1 -> Zt (LDS) + p2s/p2q partials. grid sync.
// Phase2: finalize BN2, wo2->wl (restage), H from Zt -> Ct, GEMM2 -> out.
template<int JS>
__global__ __launch_bounds__(256, 1) void k_out12(
    const _Float16* __restrict__ Opart, const float* __restrict__ Mbuf, const float* __restrict__ Lbuf,
    const float* __restrict__ wo1, const float* __restrict__ bo1,
    const float* __restrict__ go, const float* __restrict__ beo,
    const float* __restrict__ wo2, const float* __restrict__ bo2,
    float* __restrict__ p2s, float* __restrict__ p2q,
    float* __restrict__ out)
{
  __shared__ __align__(16) u16 wl[128 * 128];
  __shared__ __align__(16) u16 Ct[32 * 128];
  __shared__ __align__(16) float Zt[32][132];
  __shared__ float sc2[128], sh2[128];
  const int tid = threadIdx.x;
  // stage wo1 -> wl
  {
    const int o = tid >> 1, h = tid & 1;
    const float* wp = wo1 + o * 128 + h * 64;
    char* dst = (char*)wl + o * 256;
    const int sw = (o & 15) << 4;
    #pragma unroll
    for (int u = 0; u < 8; ++u){
      f4 a = *(const f4*)(wp + u * 8);
      f4 b = *(const f4*)(wp + u * 8 + 4);
      union { bf16x8 v; u32 uu[4]; } cc;
      cc.uu[0] = pk_bf16(a[0], a[1]); cc.uu[1] = pk_bf16(a[2], a[3]);
      cc.uu[2] = pk_bf16(b[0], b[1]); cc.uu[3] = pk_bf16(b[2], b[3]);
      *(bf16x8*)(dst + ((h * 128 + u * 16) ^ sw)) = cc.v;
    }
  }
  // combine splits -> Ct (bf16)
  {
    const int px = tid >> 3, c16 = (tid & 7) * 16;
    const int P = blockIdx.x * 32 + px;
    float coef[JS];
    float mmax = -1e30f;
    #pragma unroll
    for (int s = 0; s < JS; ++s){ coef[s] = Mbuf[s * NPIX + P]; mmax = fmaxf(mmax, coef[s]); }
    float den = 0.f;
    #pragma unroll
    for (int s = 0; s < JS; ++s){
      float w = exp2_hw(coef[s] - mmax) * Lbuf[s * NPIX + P];
      coef[s] = w; den += w;
    }
    float inv = 1.f / den;
    float a[16];
    #pragma unroll
    for (int e = 0; e < 16; ++e) a[e] = 0.f;
    #pragma unroll
    for (int s = 0; s < JS; ++s){
      float w = coef[s] * inv;
      const _Float16* op = Opart + ((size_t)s * NPIX + P) * 128 + c16;
      h8 h0 = *(const h8*)op;
      h8 h1 = *(const h8*)(op + 8);
      #pragma unroll
      for (int e = 0; e < 8; ++e){ a[e] += w * (float)h0[e]; a[8 + e] += w * (float)h1[e]; }
    }
    union { bf16x8 v; u32 uu[4]; } c0, c1;
    #pragma unroll
    for (int e = 0; e < 4; ++e){ c0.uu[e] = pk_bf16(a[e * 2], a[e * 2 + 1]); c1.uu[e] = pk_bf16(a[8 + e * 2], a[9 + e * 2]); }
    char* crow = (char*)Ct + px * 256;
    const int sw = (px & 15) << 4;
    *(bf16x8*)(crow + ((c16 * 2) ^ sw)) = c0.v;
    *(bf16x8*)(crow + ((c16 * 2 + 16) ^ sw)) = c1.v;
  }
  __syncthreads();
  const int ln = tid & 63, wid = tid >> 6, lo = ln & 31, hi = ln >> 5;
  // GEMM1: Z = C @ wo1^T + bo1
  {
    bf16x8 bfr[8];
    const char* crow = (const char*)Ct + lo * 256;
    const int swc = (lo & 15) << 4;
    #pragma unroll
    for (int kk = 0; kk < 8; ++kk)
      bfr[kk] = *(const bf16x8*)(crow + ((kk * 32 + hi * 16) ^ swc));
    f16v acc;
    #pragma unroll
    for (int r = 0; r < 16; ++r) acc[r] = 0.f;
    const int o = wid * 32 + lo;
    const char* wrow = (const char*)wl + o * 256;
    const int sww = (o & 15) << 4;
    #pragma unroll
    for (int kk = 0; kk < 8; ++kk){
      bf16x8 wf = *(const bf16x8*)(wrow + ((kk * 32 + hi * 16) ^ sww));
      acc = __builtin_amdgcn_mfma_f32_32x32x16_bf16(wf, bfr[kk], acc, 0, 0, 0);
    }
    #pragma unroll
    for (int g = 0; g < 4; ++g){
      const int o2 = wid * 32 + g * 8 + hi * 4;
      f4 b4 = *(const f4*)&bo1[o2];
      f4 zv;
      #pragma unroll
      for (int e = 0; e < 4; ++e) zv[e] = acc[g * 4 + e] + b4[e];
      *(f4*)&Zt[lo][o2] = zv;
      #pragma unroll
      for (int e = 0; e < 4; ++e){
        float sv = zv[e], qv = zv[e] * zv[e];
        #pragma unroll
        for (int msk = 1; msk < 32; msk <<= 1){ sv += __shfl_xor(sv, msk); qv += __shfl_xor(qv, msk); }
        if (lo == 0){
          p2s[blockIdx.x * 128 + o2 + e] = sv;
          p2q[blockIdx.x * 128 + o2 + e] = qv;
        }
      }
    }
  }

  cg::this_grid().sync();      // all p2s/p2q partials visible; wl free to restage

  if (tid < 128){
    float s = 0.f, q = 0.f;
    for (int i = 0; i < 200; ++i){ s += p2s[i * 128 + tid]; q += p2q[i * 128 + tid]; }
    float mean = s * (1.f / NPIX);
    float var  = q * (1.f / NPIX) - mean * mean;
    float scale = go[tid] * rsqrtf(var + 1e-5f);
    sc2[tid] = scale; sh2[tid] = beo[tid] - mean * scale;
  }
  // restage wl with wo2
  {
    const int o = tid >> 1, h = tid & 1;
    const float* wp = wo2 + o * 128 + h * 64;
    char* dst = (char*)wl + o * 256;
    const int sw = (o & 15) << 4;
    #pragma unroll
    for (int u = 0; u < 8; ++u){
      f4 a = *(const f4*)(wp + u * 8);
      f4 b = *(const f4*)(wp + u * 8 + 4);
      union { bf16x8 v; u32 uu[4]; } cc;
      cc.uu[0] = pk_bf16(a[0], a[1]); cc.uu[1] = pk_bf16(a[2], a[3]);
      cc.uu[2] = pk_bf16(b[0], b[1]); cc.uu[3] = pk_bf16(b[2], b[3]);
      *(bf16x8*)(dst + ((h * 128 + u * 16) ^ sw)) = cc.v;
    }
  }
  __syncthreads();   // sc2/sh2 + wl ready
  // H = relu(affine(Z)) -> Ct (bf16)
  {
    const int px = tid >> 3, c16 = (tid & 7) * 16;
    union { bf16x8 v; u32 uu[4]; } c0, c1;
    #pragma unroll
    for (int u = 0; u < 4; ++u){
      f4 z = *(const f4*)&Zt[px][c16 + u * 4];
      f4 s4 = *(const f4*)&sc2[c16 + u * 4];
      f4 h4v = *(const f4*)&sh2[c16 + u * 4];
      float h0 = fmaxf(z[0] * s4[0] + h4v[0], 0.f);
      float h1 = fmaxf(z[1] * s4[1] + h4v[1], 0.f);
      float h2 = fmaxf(z[2] * s4[2] + h4v[2], 0.f);
      float h3 = fmaxf(z[3] * s4[3] + h4v[3], 0.f);
      u32 lo32 = pk_bf16(h0, h1), hi32 = pk_bf16(h2, h3);
      if (u < 2){ c0.uu[u * 2] = lo32; c0.uu[u * 2 + 1] = hi32; }
      else { c1.uu[(u - 2) * 2] = lo32; c1.uu[(u - 2) * 2 + 1] = hi32; }
    }
    char* crow = (char*)Ct + px * 256;
    const int sw = (px & 15) << 4;
    *(bf16x8*)(crow + ((c16 * 2) ^ sw)) = c0.v;
    *(bf16x8*)(crow + ((c16 * 2 + 16) ^ sw)) = c1.v;
  }
  __syncthreads();
  // GEMM2: out = wo2 @ H + bo2
  {
    const int p = blockIdx.x * 32 + lo;
    bf16x8 bfH[8];
    const char* crow = (const char*)Ct + lo * 256;
    const int swc = (lo & 15) << 4;
    #pragma unroll
    for (int kk = 0; kk < 8; ++kk)
      bfH[kk] = *(const bf16x8*)(crow + ((kk * 32 + hi * 16) ^ swc));
    f16v acc;
    #pragma unroll
    for (int r = 0; r < 16; ++r) acc[r] = 0.f;
    const int o = wid * 32 + lo;
    const char* wrow = (const char*)wl + o * 256;
    const int sww = (o & 15) << 4;
    #pragma unroll
    for (int kk = 0; kk < 8; ++kk){
      bf16x8 wf = *(const bf16x8*)(wrow + ((kk * 32 + hi * 16) ^ sww));
      acc = __builtin_amdgcn_mfma_f32_32x32x16_bf16(wf, bfH[kk], acc, 0, 0, 0);
    }
    #pragma unroll
    for (int g = 0; g < 4; ++g){
      const int o3 = wid * 32 + g * 8 + hi * 4;
      f4 b4 = *(const f4*)&bo2[o3];
      #pragma unroll
      for (int e = 0; e < 4; ++e)
        out[(size_t)(o3 + e) * NPIX + p] = acc[g * 4 + e] + b4[e];
    }
  }
}

extern "C" void kernel_launch(void* const* d_in, const int* in_sizes, int n_in,
                              void* d_out, int out_size, void* d_ws, size_t ws_size,
                              hipStream_t stream)
{
  const float* query = (const float*)d_in[0];
  const float* key_  = (const float*)d_in[1];
  const float* value = (const float*)d_in[2];
  const float* pos   = (const float*)d_in[3];
  const float* wq = (const float*)d_in[4];  const float* bq = (const float*)d_in[5];
  const float* gq = (const float*)d_in[6];  const float* betaq = (const float*)d_in[7];
  const float* wk = (const float*)d_in[8];  const float* bk = (const float*)d_in[9];
  const float* gk = (const float*)d_in[10]; const float* betak = (const float*)d_in[11];
  const float* wv = (const float*)d_in[12]; const float* bv = (const float*)d_in[13];
  const float* gv = (const float*)d_in[14]; const float* betav = (const float*)d_in[15];
  const float* wo1 = (const float*)d_in[16]; const float* bo1 = (const float*)d_in[17];
  const float* go  = (const float*)d_in[18]; const float* betao = (const float*)d_in[19];
  const float* wo2 = (const float*)d_in[20]; const float* bo2 = (const float*)d_in[21];

  const size_t fixed = 5299200;            // q2,k2,v2t,rowsumq,psum,psq,p2s,p2q
  auto need = [&](int j) -> size_t {
    return fixed + (size_t)j * 51200 + (size_t)j * 1638400;   // M+L + Opart fp16
  };
  int js = 5;
  if (ws_size >= need(10)) js = 10;        // 250 flash blocks = full machine, one round

  char* W = (char*)d_ws;
  size_t off = 0;
  auto alloc = [&](size_t n){ char* p = W + off; off += n; return p; };
  u16*  q2      = (u16*)alloc(1638400);
  u16*  k2      = (u16*)alloc(1638400);
  u16*  v2t     = (u16*)alloc(1638400);
  float* rowsumq= (float*)alloc(25600);
  float* psum   = (float*)alloc(76800);
  float* psq    = (float*)alloc(76800);
  float* p2s    = (float*)alloc(102400);
  float* p2q    = (float*)alloc(102400);
  float* Mbuf   = (float*)alloc((size_t)js * 25600);
  float* Lbuf   = (float*)alloc((size_t)js * 25600);
  _Float16* Opart = (_Float16*)alloc((size_t)js * 1638400);
  float* outp   = (float*)d_out;

  {
    void* args[] = {
      (void*)&query, (void*)&key_, (void*)&value,
      (void*)&wq, (void*)&bq, (void*)&wk, (void*)&bk, (void*)&wv, (void*)&bv,
      (void*)&gq, (void*)&betaq, (void*)&gk, (void*)&betak, (void*)&gv, (void*)&betav,
      (void*)&q2, (void*)&k2, (void*)&v2t, (void*)&rowsumq, (void*)&psum, (void*)&psq
    };
    hipLaunchCooperativeKernel((void*)k_projnorm, dim3(150), dim3(512), args, 0, stream);
  }
  if (js == 10){
    k_flash<10><<<dim3(250), dim3(512), 0, stream>>>(q2, k2, v2t, rowsumq, pos, Opart, Mbuf, Lbuf, 10);
    void* args[] = {
      (void*)&Opart, (void*)&Mbuf, (void*)&Lbuf, (void*)&wo1, (void*)&bo1,
      (void*)&go, (void*)&betao, (void*)&wo2, (void*)&bo2,
      (void*)&p2s, (void*)&p2q, (void*)&outp
    };
    hipLaunchCooperativeKernel((void*)(&k_out12<10>), dim3(200), dim3(256), args, 0, stream);
  } else {
    k_flash<20><<<dim3(125), dim3(512), 0, stream>>>(q2, k2, v2t, rowsumq, pos, Opart, Mbuf, Lbuf, 5);
    void* args[] = {
      (void*)&Opart, (void*)&Mbuf, (void*)&Lbuf, (void*)&wo1, (void*)&bo1,
      (void*)&go, (void*)&betao, (void*)&wo2, (void*)&bo2,
      (void*)&p2s, (void*)&p2q, (void*)&outp
    };
    hipLaunchCooperativeKernel((void*)(&k_out12<5>), dim3(200), dim3(256), args, 0, stream);
  }
}

// Round 14
// 86.822 us; speedup vs baseline: 1.6398x; 1.6398x over previous
//
#include <hip/hip_runtime.h>

#define NPIX 6400

typedef float f4 __attribute__((ext_vector_type(4)));
typedef float f16v __attribute__((ext_vector_type(16)));
typedef short bf16x8 __attribute__((ext_vector_type(8)));
typedef unsigned int u4 __attribute__((ext_vector_type(4)));
typedef unsigned int u2 __attribute__((ext_vector_type(2)));
typedef _Float16 h8 __attribute__((ext_vector_type(8)));
typedef _Float16 h4 __attribute__((ext_vector_type(4)));
typedef unsigned short u16;
typedef unsigned int u32;

__device__ __forceinline__ u16 f2bf(float f){
  union { float f; u32 u; } v; v.f = f;
  u32 r = v.u + 0x7fffu + ((v.u >> 16) & 1u);
  return (u16)(r >> 16);
}
__device__ __forceinline__ float bf2f(u16 h){
  union { u32 u; float f; } v; v.u = (u32)h << 16; return v.f;
}
__device__ __forceinline__ u32 pk_bf16(float lo, float hi){
  u32 r;
  asm("v_cvt_pk_bf16_f32 %0, %1, %2" : "=v"(r) : "v"(lo), "v"(hi));
  return r;
}
__device__ __forceinline__ float exp2_hw(float x){ return __builtin_amdgcn_exp2f(x); }

// ---------------- K1: projection GEMMs (fp32 compute, bf16 Y out) + BN partial stats ----------
// grid 150: proj = bid/50, pt = bid%50 (128-pixel tile)  [R10/R12 structure — proven]
__global__ __launch_bounds__(512, 1) void k_proj(
    const float* __restrict__ xq, const float* __restrict__ xk, const float* __restrict__ xv,
    const float* __restrict__ wq, const float* __restrict__ bq,
    const float* __restrict__ wk, const float* __restrict__ bk,
    const float* __restrict__ wv, const float* __restrict__ bv,
    u16* __restrict__ Y, float* __restrict__ psum, float* __restrict__ psq)
{
  __shared__ __align__(16) float wT[64][132];
  __shared__ __align__(16) float xt[64][132];
  __shared__ __align__(16) float red[2][16][128];
  const int bid = blockIdx.x;
  const int proj = bid / 50, pt = bid % 50;
  const float* x = (proj == 0) ? xq : ((proj == 1) ? xk : xv);
  const float* w = (proj == 0) ? wq : ((proj == 1) ? wk : wv);
  const float* b = (proj == 0) ? bq : ((proj == 1) ? bk : bv);
  const int t = threadIdx.x;
  const int o0 = (t & 31) * 4, p0 = (t >> 5) * 8;
  float acc[4][8];
  #pragma unroll
  for (int i = 0; i < 4; ++i)
    #pragma unroll
    for (int j = 0; j < 8; ++j) acc[i][j] = 0.f;
  for (int cc = 0; cc < 2; ++cc){
    __syncthreads();
    for (int idx = t; idx < 2048; idx += 512){
      int o = idx >> 4, c4 = (idx & 15) * 4;
      f4 wv4 = *(const f4*)&w[o * 128 + cc * 64 + c4];
      wT[c4 + 0][o] = wv4[0]; wT[c4 + 1][o] = wv4[1];
      wT[c4 + 2][o] = wv4[2]; wT[c4 + 3][o] = wv4[3];
    }
    for (int idx = t; idx < 2048; idx += 512){
      int c = idx >> 5, p4 = (idx & 31) * 4;
      *(f4*)&xt[c][p4] = *(const f4*)&x[(cc * 64 + c) * NPIX + pt * 128 + p4];
    }
    __syncthreads();
    for (int c = 0; c < 64; ++c){
      f4 w4 = *(const f4*)&wT[c][o0];
      f4 x0 = *(const f4*)&xt[c][p0];
      f4 x1 = *(const f4*)&xt[c][p0 + 4];
      #pragma unroll
      for (int i = 0; i < 4; ++i){
        float wi = w4[i];
        #pragma unroll
        for (int j = 0; j < 4; ++j){ acc[i][j] += wi * x0[j]; acc[i][4 + j] += wi * x1[j]; }
      }
    }
  }
  f4 b4 = *(const f4*)&b[o0];
  #pragma unroll
  for (int i = 0; i < 4; ++i)
    #pragma unroll
    for (int j = 0; j < 8; ++j) acc[i][j] += b4[i];
  #pragma unroll
  for (int i = 0; i < 4; ++i){
    float s = 0.f, q = 0.f;
    #pragma unroll
    for (int j = 0; j < 8; ++j){ s += acc[i][j]; q += acc[i][j] * acc[i][j]; }
    red[0][t >> 5][o0 + i] = s;
    red[1][t >> 5][o0 + i] = q;
  }
  __syncthreads();
  if (t < 128){
    float s = 0.f, q = 0.f;
    #pragma unroll
    for (int g = 0; g < 16; ++g){ s += red[0][g][t]; q += red[1][g][t]; }
    psum[(proj * 50 + pt) * 128 + t] = s;
    psq [(proj * 50 + pt) * 128 + t] = q;
  }
  u16* Yb = Y + (size_t)proj * NPIX * 128;
  if (proj < 2){
    #pragma unroll
    for (int j = 0; j < 8; ++j){
      u2 v;
      v[0] = (u32)f2bf(acc[0][j]) | ((u32)f2bf(acc[1][j]) << 16);
      v[1] = (u32)f2bf(acc[2][j]) | ((u32)f2bf(acc[3][j]) << 16);
      *(u2*)&Yb[(size_t)(pt * 128 + p0 + j) * 128 + o0] = v;
    }
  } else {
    #pragma unroll
    for (int i = 0; i < 4; ++i){
      u4 v;
      #pragma unroll
      for (int jj = 0; jj < 4; ++jj)
        v[jj] = (u32)f2bf(acc[i][jj * 2]) | ((u32)f2bf(acc[i][jj * 2 + 1]) << 16);
      *(u4*)&Yb[(size_t)(o0 + i) * NPIX + pt * 128 + p0] = v;
    }
  }
}

// ---------------- K2: finalize BN + normalize+ReLU+bf16; Q pre-scaled by 1/sqrt(128)/ln2 ----
// grid 150: proj = bid/50, pt = bid%50 (128-pixel tile)  [R12 structure — proven]
__global__ __launch_bounds__(512, 1) void k_norm(
    const u16* __restrict__ Y, const float* __restrict__ psum, const float* __restrict__ psq,
    const float* __restrict__ gq, const float* __restrict__ beq,
    const float* __restrict__ gk, const float* __restrict__ bek,
    const float* __restrict__ gv, const float* __restrict__ bev,
    u16* __restrict__ q2, u16* __restrict__ k2, u16* __restrict__ v2t,
    float* __restrict__ rowsumq)
{
  __shared__ float sc[128], sh[128];
  const int bid = blockIdx.x, t = threadIdx.x;
  const int proj = bid / 50, pt = bid % 50;
  if (t < 128){
    float s = 0.f, q = 0.f;
    for (int i = 0; i < 50; ++i){
      s += psum[(proj * 50 + i) * 128 + t];
      q += psq [(proj * 50 + i) * 128 + t];
    }
    float mean = s * (1.f / NPIX);
    float var  = q * (1.f / NPIX) - mean * mean;
    const float* g  = (proj == 0) ? gq : ((proj == 1) ? gk : gv);
    const float* be = (proj == 0) ? beq : ((proj == 1) ? bek : bev);
    float scale = g[t] * rsqrtf(var + 1e-5f);
    sc[t] = scale; sh[t] = be[t] - mean * scale;
  }
  __syncthreads();
  const u16* Yb = Y + (size_t)proj * NPIX * 128;
  const float qs_l2 = 0.12751700f;      // 1/sqrt(128)/ln2 folded into Q
  if (proj < 2){
    int row = pt * 128 + (t >> 2), o0 = (t & 3) * 32;
    const float oscale = (proj == 0) ? qs_l2 : 1.f;
    float rs = 0.f;
    u32 pkd[16];
    #pragma unroll
    for (int u = 0; u < 4; ++u){
      bf16x8 y8 = *(const bf16x8*)&Yb[(size_t)row * 128 + o0 + u * 8];
      #pragma unroll
      for (int e = 0; e < 8; ++e){
        int o = o0 + u * 8 + e;
        float v = fmaxf(bf2f((u16)y8[e]) * sc[o] + sh[o], 0.f);
        rs += v;
        float ov = v * oscale;
        if ((e & 1) == 0) pkd[u * 4 + (e >> 1)] = (u32)f2bf(ov);
        else pkd[u * 4 + (e >> 1)] |= ((u32)f2bf(ov) << 16);
      }
    }
    u16* dst = (proj == 0) ? q2 : k2;
    u4* dp = (u4*)(dst + (size_t)row * 128 + o0);
    #pragma unroll
    for (int u = 0; u < 4; ++u){
      u4 v; v[0] = pkd[u*4]; v[1] = pkd[u*4+1]; v[2] = pkd[u*4+2]; v[3] = pkd[u*4+3];
      dp[u] = v;
    }
    if (proj == 0){
      rs += __shfl_xor(rs, 1);
      rs += __shfl_xor(rs, 2);
      if ((t & 3) == 0) rowsumq[row] = rs * 1.4426950408889634f;   // 1/ln2 folded
    }
  } else {
    int o = t >> 2, pc = pt * 128 + (t & 3) * 32;
    float scale = sc[o], shift = sh[o];
    u32 pkd[16];
    #pragma unroll
    for (int u = 0; u < 4; ++u){
      bf16x8 y8 = *(const bf16x8*)&Yb[(size_t)o * NPIX + pc + u * 8];
      #pragma unroll
      for (int e = 0; e < 8; ++e){
        float v = fmaxf(bf2f((u16)y8[e]) * scale + shift, 0.f);
        if ((e & 1) == 0) pkd[u * 4 + (e >> 1)] = (u32)f2bf(v);
        else pkd[u * 4 + (e >> 1)] |= ((u32)f2bf(v) << 16);
      }
    }
    u4* dp = (u4*)(v2t + (size_t)o * NPIX + pc);
    #pragma unroll
    for (int u = 0; u < 4; ++u){
      u4 v; v[0] = pkd[u*4]; v[1] = pkd[u*4+1]; v[2] = pkd[u*4+2]; v[3] = pkd[u*4+3];
      dp[u] = v;
    }
  }
}

// ---------------- K3: flash attention, 512 thr, LDS dbuf, 4-way QK ILP, NKT compile-time ----
// Only change vs R12: softmax P-pack uses v_cvt_pk_bf16_f32 (1 instr/2 vals vs ~8 VALU)
template<int NKT>
__global__ __launch_bounds__(512, 2) void k_flash(
    const u16* __restrict__ q2, const u16* __restrict__ k2, const u16* __restrict__ v2t,
    const float* __restrict__ rowsumq, const float* __restrict__ pos,
    _Float16* __restrict__ Opart, float* __restrict__ Mout, float* __restrict__ Lout,
    int js)
{
  __shared__ __align__(16) u16 Kt[2][64 * 128];
  __shared__ __align__(16) u16 Vt[2][128 * 64];
  __shared__ __align__(16) float posT[2][64];
  const int bid = blockIdx.x;
  const int qb = bid / js, jsi = bid % js;
  const int kt0 = jsi * NKT;
  const int tid = threadIdx.x;
  const int ln = tid & 63, wid = tid >> 6;
  const int lo = ln & 31, hi = ln >> 5;
  const int qrow = qb * 256 + wid * 32 + lo;

  const int kc_j = tid >> 4, kc_c8 = tid & 15;
  const int vc_d = tid >> 3, vc_c8 = tid & 7;
  bf16x8 kreg0, kreg1, vreg0, vreg1; float posr = 0.f;
  auto stage_load = [&](int j0){
    kreg0 = *(const bf16x8*)(k2 + (size_t)(j0 + kc_j) * 128 + kc_c8 * 8);
    kreg1 = *(const bf16x8*)(k2 + (size_t)(j0 + kc_j + 32) * 128 + kc_c8 * 8);
    vreg0 = *(const bf16x8*)(v2t + (size_t)vc_d * NPIX + j0 + vc_c8 * 8);
    vreg1 = *(const bf16x8*)(v2t + (size_t)(vc_d + 64) * NPIX + j0 + vc_c8 * 8);
    if (tid < 64) posr = pos[j0 + tid];
  };
  auto stage_write = [&](int b){
    char* kb = (char*)&Kt[b][0];
    char* vb = (char*)&Vt[b][0];
    *(bf16x8*)(kb + kc_j * 256 + ((kc_c8 * 16) ^ ((kc_j & 15) << 4))) = kreg0;
    *(bf16x8*)(kb + (kc_j + 32) * 256 + ((kc_c8 * 16) ^ (((kc_j + 32) & 15) << 4))) = kreg1;
    *(bf16x8*)(vb + vc_d * 128 + ((vc_c8 * 16) ^ ((vc_d & 7) << 4))) = vreg0;
    *(bf16x8*)(vb + (vc_d + 64) * 128 + ((vc_c8 * 16) ^ (((vc_d + 64) & 7) << 4))) = vreg1;
    if (tid < 64) posT[b][tid] = posr;
  };

  bf16x8 qf[8];
  const u16* qp = q2 + (size_t)qrow * 128 + hi * 8;
  #pragma unroll
  for (int kk = 0; kk < 8; ++kk) qf[kk] = *(const bf16x8*)(qp + kk * 16);
  const float rsq_l2 = rowsumq[qrow];          // pre-multiplied by 1/ln2 in k_norm
  f16v accO[4];
  #pragma unroll
  for (int c = 0; c < 4; ++c)
    #pragma unroll
    for (int r = 0; r < 16; ++r) accO[c][r] = 0.f;
  float m = -1e30f, l = 0.f;

  stage_load(kt0 * 64);
  stage_write(0);
  __syncthreads();
  int cur = 0;

  #pragma unroll 2
  for (int kt = 0; kt < NKT; ++kt){
    const bool more = (kt + 1 < NKT);
    if (more) stage_load((kt0 + kt + 1) * 64);

    f16v aS0a, aS0b, aS1a, aS1b;
    #pragma unroll
    for (int r = 0; r < 16; ++r){ aS0a[r] = 0.f; aS0b[r] = 0.f; aS1a[r] = 0.f; aS1b[r] = 0.f; }
    {
      const char* kb0 = (const char*)&Kt[cur][0] + lo * 256;
      const char* kb1 = (const char*)&Kt[cur][0] + (32 + lo) * 256;
      const int sw = (lo & 15) << 4;
      #pragma unroll
      for (int kk = 0; kk < 4; ++kk){
        int boA = (kk * 32 + hi * 16) ^ sw;
        int boB = ((kk + 4) * 32 + hi * 16) ^ sw;
        bf16x8 kf0a = *(const bf16x8*)(kb0 + boA);
        bf16x8 kf1a = *(const bf16x8*)(kb1 + boA);
        bf16x8 kf0b = *(const bf16x8*)(kb0 + boB);
        bf16x8 kf1b = *(const bf16x8*)(kb1 + boB);
        aS0a = __builtin_amdgcn_mfma_f32_32x32x16_bf16(kf0a, qf[kk], aS0a, 0, 0, 0);
        aS1a = __builtin_amdgcn_mfma_f32_32x32x16_bf16(kf1a, qf[kk], aS1a, 0, 0, 0);
        aS0b = __builtin_amdgcn_mfma_f32_32x32x16_bf16(kf0b, qf[kk + 4], aS0b, 0, 0, 0);
        aS1b = __builtin_amdgcn_mfma_f32_32x32x16_bf16(kf1b, qf[kk + 4], aS1b, 0, 0, 0);
      }
    }
    float pv[32];
    float mx = -1e30f;
    #pragma unroll
    for (int jsb = 0; jsb < 2; ++jsb){
      #pragma unroll
      for (int g = 0; g < 4; ++g){
        f4 p4 = *(const f4*)&posT[cur][jsb * 32 + g * 8 + hi * 4];
        #pragma unroll
        for (int e = 0; e < 4; ++e){
          float sraw = jsb ? (aS1a[g * 4 + e] + aS1b[g * 4 + e])
                           : (aS0a[g * 4 + e] + aS0b[g * 4 + e]);
          float sv = sraw + rsq_l2 * p4[e];     // log2-domain (Q pre-scaled)
          pv[jsb * 16 + g * 4 + e] = sv;
          mx = fmaxf(mx, sv);
        }
      }
    }
    mx = fmaxf(mx, __shfl_xor(mx, 32));
    if (!__all(mx - m <= 11.5f)){
      float mnew = fmaxf(m, mx);
      float corr = exp2_hw(m - mnew);
      m = mnew;
      l *= corr;
      #pragma unroll
      for (int c = 0; c < 4; ++c)
        #pragma unroll
        for (int r = 0; r < 16; ++r) accO[c][r] *= corr;
    }
    float ls = 0.f;
    u32 pk[16];
    #pragma unroll
    for (int i = 0; i < 16; ++i){
      float e0 = exp2_hw(pv[2 * i]     - m);
      float e1 = exp2_hw(pv[2 * i + 1] - m);
      ls += e0 + e1;
      pk[i] = pk_bf16(e0, e1);               // 1 VALU instead of ~8
    }
    ls += __shfl_xor(ls, 32);
    l += ls;

    if (more) stage_write(cur ^ 1);

    #pragma unroll
    for (int w = 0; w < 4; ++w){
      const int b0 = (w >> 1) * 8 + (w & 1) * 4;
      u32 s0 = __shfl_xor(pk[b0], 32);
      u32 s1 = __shfl_xor(pk[b0 + 1], 32);
      u32 s2 = __shfl_xor(pk[b0 + 2], 32);
      u32 s3 = __shfl_xor(pk[b0 + 3], 32);
      union { bf16x8 v; u32 u[4]; } pf;
      pf.u[0] = hi ? s2 : pk[b0];
      pf.u[1] = hi ? s3 : pk[b0 + 1];
      pf.u[2] = hi ? pk[b0 + 2] : s0;
      pf.u[3] = hi ? pk[b0 + 3] : s1;
      #pragma unroll
      for (int c = 0; c < 4; ++c){
        int d = c * 32 + lo;
        bf16x8 vf = *(const bf16x8*)((const char*)&Vt[cur][0] + d * 128 + ((w * 32 + hi * 16) ^ ((d & 7) << 4)));
        accO[c] = __builtin_amdgcn_mfma_f32_32x32x16_bf16(vf, pf.v, accO[c], 0, 0, 0);
      }
    }
    if (more) __syncthreads();
    cur ^= 1;
  }
  if (hi == 0){
    Mout[jsi * NPIX + qrow] = m;
    Lout[jsi * NPIX + qrow] = l;
  }
  const float linv = 1.f / l;
  _Float16* Ob = Opart + ((size_t)jsi * NPIX + qrow) * 128;
  #pragma unroll
  for (int c = 0; c < 4; ++c){
    #pragma unroll
    for (int g = 0; g < 4; ++g){
      h4 hv;
      #pragma unroll
      for (int e = 0; e < 4; ++e) hv[e] = (_Float16)(accO[c][g * 4 + e] * linv);
      *(h4*)&Ob[c * 32 + g * 8 + hi * 4] = hv;
    }
  }
}

// ---------------- K4: fused combine + Z = O@wo1^T + bo1 + BN2 partials (200 x 256) ----------
template<int JS>
__global__ __launch_bounds__(256, 1) void k_out1(
    const _Float16* __restrict__ Opart, const float* __restrict__ Mbuf, const float* __restrict__ Lbuf,
    const float* __restrict__ wo1, const float* __restrict__ bo1,
    float* __restrict__ Z, float* __restrict__ p2s, float* __restrict__ p2q)
{
  __shared__ __align__(16) u16 wl[128 * 128];
  __shared__ __align__(16) u16 Ct[32 * 128];
  const int tid = threadIdx.x;
  {
    const int o = tid >> 1, h = tid & 1;
    const float* wp = wo1 + o * 128 + h * 64;
    char* dst = (char*)wl + o * 256;
    const int sw = (o & 15) << 4;
    #pragma unroll
    for (int u = 0; u < 8; ++u){
      f4 a = *(const f4*)(wp + u * 8);
      f4 b = *(const f4*)(wp + u * 8 + 4);
      union { bf16x8 v; u16 s[8]; } cc;
      #pragma unroll
      for (int e = 0; e < 4; ++e){ cc.s[e] = f2bf(a[e]); cc.s[4 + e] = f2bf(b[e]); }
      *(bf16x8*)(dst + ((h * 128 + u * 16) ^ sw)) = cc.v;
    }
  }
  {
    const int px = tid >> 3, c16 = (tid & 7) * 16;
    const int P = blockIdx.x * 32 + px;
    float coef[JS];
    float mmax = -1e30f;
    #pragma unroll
    for (int s = 0; s < JS; ++s){ coef[s] = Mbuf[s * NPIX + P]; mmax = fmaxf(mmax, coef[s]); }
    float den = 0.f;
    #pragma unroll
    for (int s = 0; s < JS; ++s){
      float w = exp2_hw(coef[s] - mmax) * Lbuf[s * NPIX + P];
      coef[s] = w; den += w;
    }
    float inv = 1.f / den;
    float a[16];
    #pragma unroll
    for (int e = 0; e < 16; ++e) a[e] = 0.f;
    #pragma unroll
    for (int s = 0; s < JS; ++s){
      float w = coef[s] * inv;
      const _Float16* op = Opart + ((size_t)s * NPIX + P) * 128 + c16;
      h8 h0 = *(const h8*)op;
      h8 h1 = *(const h8*)(op + 8);
      #pragma unroll
      for (int e = 0; e < 8; ++e){ a[e] += w * (float)h0[e]; a[8 + e] += w * (float)h1[e]; }
    }
    union { bf16x8 v; u16 s[8]; } c0, c1;
    #pragma unroll
    for (int e = 0; e < 8; ++e){ c0.s[e] = f2bf(a[e]); c1.s[e] = f2bf(a[8 + e]); }
    char* crow = (char*)Ct + px * 256;
    const int sw = (px & 15) << 4;
    *(bf16x8*)(crow + ((c16 * 2) ^ sw)) = c0.v;
    *(bf16x8*)(crow + ((c16 * 2 + 16) ^ sw)) = c1.v;
  }
  __syncthreads();
  const int ln = tid & 63, wid = tid >> 6, lo = ln & 31, hi = ln >> 5;
  const int p = blockIdx.x * 32 + lo;
  bf16x8 bfr[8];
  {
    const char* crow = (const char*)Ct + lo * 256;
    const int sw = (lo & 15) << 4;
    #pragma unroll
    for (int kk = 0; kk < 8; ++kk)
      bfr[kk] = *(const bf16x8*)(crow + ((kk * 32 + hi * 16) ^ sw));
  }
  f16v acc;
  #pragma unroll
  for (int r = 0; r < 16; ++r) acc[r] = 0.f;
  {
    const int o = wid * 32 + lo;
    const char* wrow = (const char*)wl + o * 256;
    const int sw = (o & 15) << 4;
    #pragma unroll
    for (int kk = 0; kk < 8; ++kk){
      bf16x8 wf = *(const bf16x8*)(wrow + ((kk * 32 + hi * 16) ^ sw));
      acc = __builtin_amdgcn_mfma_f32_32x32x16_bf16(wf, bfr[kk], acc, 0, 0, 0);
    }
  }
  #pragma unroll
  for (int g = 0; g < 4; ++g){
    const int o2 = wid * 32 + g * 8 + hi * 4;
    f4 b4 = *(const f4*)&bo1[o2];
    f4 zv;
    #pragma unroll
    for (int e = 0; e < 4; ++e) zv[e] = acc[g * 4 + e] + b4[e];
    *(f4*)&Z[(size_t)p * 128 + o2] = zv;
    #pragma unroll
    for (int e = 0; e < 4; ++e){
      float sv = zv[e], qv = zv[e] * zv[e];
      #pragma unroll
      for (int msk = 1; msk < 32; msk <<= 1){ sv += __shfl_xor(sv, msk); qv += __shfl_xor(qv, msk); }
      if (lo == 0){
        p2s[blockIdx.x * 128 + o2 + e] = sv;
        p2q[blockIdx.x * 128 + o2 + e] = qv;
      }
    }
  }
}

// ---------------- K5: BN2 + H=relu(affine(Z)) + out = wo2@H + bo2 (200 x 256, 32 px/block) ----
__global__ __launch_bounds__(256, 1) void k_out2(
    const float* __restrict__ Z, const float* __restrict__ p2s, const float* __restrict__ p2q,
    const float* __restrict__ go, const float* __restrict__ beo,
    const float* __restrict__ wo2, const float* __restrict__ bo2,
    float* __restrict__ out)
{
  __shared__ __align__(16) u16 wl[128 * 128];
  __shared__ __align__(16) u16 Ct[32 * 128];
  __shared__ float sc2[128], sh2[128];
  const int tid = threadIdx.x;
  if (tid < 128){
    float s = 0.f, q = 0.f;
    for (int i = 0; i < 200; ++i){ s += p2s[i * 128 + tid]; q += p2q[i * 128 + tid]; }
    float mean = s * (1.f / NPIX);
    float var  = q * (1.f / NPIX) - mean * mean;
    float scale = go[tid] * rsqrtf(var + 1e-5f);
    sc2[tid] = scale; sh2[tid] = beo[tid] - mean * scale;
  }
  {
    const int o = tid >> 1, h = tid & 1;
    const float* wp = wo2 + o * 128 + h * 64;
    char* dst = (char*)wl + o * 256;
    const int sw = (o & 15) << 4;
    #pragma unroll
    for (int u = 0; u < 8; ++u){
      f4 a = *(const f4*)(wp + u * 8);
      f4 b = *(const f4*)(wp + u * 8 + 4);
      union { bf16x8 v; u16 s[8]; } cc;
      #pragma unroll
      for (int e = 0; e < 4; ++e){ cc.s[e] = f2bf(a[e]); cc.s[4 + e] = f2bf(b[e]); }
      *(bf16x8*)(dst + ((h * 128 + u * 16) ^ sw)) = cc.v;
    }
  }
  __syncthreads();   // sc2/sh2 ready before H build
  {
    const int px = tid >> 3, c16 = (tid & 7) * 16;
    const int P = blockIdx.x * 32 + px;
    union { bf16x8 v; u16 s[8]; } c0, c1;
    #pragma unroll
    for (int u = 0; u < 4; ++u){
      f4 z = *(const f4*)&Z[(size_t)P * 128 + c16 + u * 4];
      f4 s4 = *(const f4*)&sc2[c16 + u * 4];
      f4 h4v = *(const f4*)&sh2[c16 + u * 4];
      #pragma unroll
      for (int e = 0; e < 4; ++e){
        u16 hb = f2bf(fmaxf(z[e] * s4[e] + h4v[e], 0.f));
        if (u < 2) c0.s[u * 4 + e] = hb; else c1.s[(u - 2) * 4 + e] = hb;
      }
    }
    char* crow = (char*)Ct + px * 256;
    const int sw = (px & 15) << 4;
    *(bf16x8*)(crow + ((c16 * 2) ^ sw)) = c0.v;
    *(bf16x8*)(crow + ((c16 * 2 + 16) ^ sw)) = c1.v;
  }
  __syncthreads();
  const int ln = tid & 63, wid = tid >> 6, lo = ln & 31, hi = ln >> 5;
  const int p = blockIdx.x * 32 + lo;
  bf16x8 bfH[8];
  {
    const char* crow = (const char*)Ct + lo * 256;
    const int sw = (lo & 15) << 4;
    #pragma unroll
    for (int kk = 0; kk < 8; ++kk)
      bfH[kk] = *(const bf16x8*)(crow + ((kk * 32 + hi * 16) ^ sw));
  }
  f16v acc;
  #pragma unroll
  for (int r = 0; r < 16; ++r) acc[r] = 0.f;
  {
    const int o = wid * 32 + lo;
    const char* wrow = (const char*)wl + o * 256;
    const int sw = (o & 15) << 4;
    #pragma unroll
    for (int kk = 0; kk < 8; ++kk){
      bf16x8 wf = *(const bf16x8*)(wrow + ((kk * 32 + hi * 16) ^ sw));
      acc = __builtin_amdgcn_mfma_f32_32x32x16_bf16(wf, bfH[kk], acc, 0, 0, 0);
    }
  }
  #pragma unroll
  for (int g = 0; g < 4; ++g){
    const int o3 = wid * 32 + g * 8 + hi * 4;
    f4 b4 = *(const f4*)&bo2[o3];
    #pragma unroll
    for (int e = 0; e < 4; ++e)
      out[(size_t)(o3 + e) * NPIX + p] = acc[g * 4 + e] + b4[e];
  }
}

extern "C" void kernel_launch(void* const* d_in, const int* in_sizes, int n_in,
                              void* d_out, int out_size, void* d_ws, size_t ws_size,
                              hipStream_t stream)
{
  const float* query = (const float*)d_in[0];
  const float* key_  = (const float*)d_in[1];
  const float* value = (const float*)d_in[2];
  const float* pos   = (const float*)d_in[3];
  const float* wq = (const float*)d_in[4];  const float* bq = (const float*)d_in[5];
  const float* gq = (const float*)d_in[6];  const float* betaq = (const float*)d_in[7];
  const float* wk = (const float*)d_in[8];  const float* bk = (const float*)d_in[9];
  const float* gk = (const float*)d_in[10]; const float* betak = (const float*)d_in[11];
  const float* wv = (const float*)d_in[12]; const float* bv = (const float*)d_in[13];
  const float* gv = (const float*)d_in[14]; const float* betav = (const float*)d_in[15];
  const float* wo1 = (const float*)d_in[16]; const float* bo1 = (const float*)d_in[17];
  const float* go  = (const float*)d_in[18]; const float* betao = (const float*)d_in[19];
  const float* wo2 = (const float*)d_in[20]; const float* bo2 = (const float*)d_in[21];

  // Opart fp16 normalized; Y is bf16 (4.9 MB) overlaid by Opart
  const size_t fixed = 8576000;            // q2,k2,v2t,rowsumq,psum,psq,Z,p2s,p2q
  auto need = [&](int j) -> size_t {
    size_t ml = (size_t)j * 51200;         // M + L
    size_t op = (size_t)j * 1638400;       // Opart fp16
    size_t ov = op > 4915200 ? op : (size_t)4915200;  // overlays Y (bf16)
    return fixed + ml + ov;
  };
  int js = 5;
  if (ws_size >= need(10)) js = 10;        // 250 blocks = full machine, one round

  char* W = (char*)d_ws;
  size_t off = 0;
  auto alloc = [&](size_t n){ char* p = W + off; off += n; return p; };
  u16*  q2      = (u16*)alloc(1638400);
  u16*  k2      = (u16*)alloc(1638400);
  u16*  v2t     = (u16*)alloc(1638400);
  float* rowsumq= (float*)alloc(25600);
  float* psum   = (float*)alloc(76800);
  float* psq    = (float*)alloc(76800);
  float* Z      = (float*)alloc(3276800);
  float* p2s    = (float*)alloc(102400);
  float* p2q    = (float*)alloc(102400);
  float* Mbuf   = (float*)alloc((size_t)js * 25600);
  float* Lbuf   = (float*)alloc((size_t)js * 25600);
  u16*  Y       = (u16*)(W + off);         // bf16 Yq,Yk,Yv (dead after k_norm)
  _Float16* Opart = (_Float16*)(W + off);  // overlays Y

  k_proj <<<dim3(150), dim3(512), 0, stream>>>(query, key_, value, wq, bq, wk, bk, wv, bv, Y, psum, psq);
  k_norm <<<dim3(150), dim3(512), 0, stream>>>(Y, psum, psq, gq, betaq, gk, betak, gv, betav, q2, k2, v2t, rowsumq);
  if (js == 10){
    k_flash<10><<<dim3(25 * 10), dim3(512), 0, stream>>>(q2, k2, v2t, rowsumq, pos, Opart, Mbuf, Lbuf, 10);
    k_out1<10><<<dim3(200), dim3(256), 0, stream>>>(Opart, Mbuf, Lbuf, wo1, bo1, Z, p2s, p2q);
  } else {
    k_flash<20><<<dim3(25 * 5), dim3(512), 0, stream>>>(q2, k2, v2t, rowsumq, pos, Opart, Mbuf, Lbuf, 5);
    k_out1<5><<<dim3(200), dim3(256), 0, stream>>>(Opart, Mbuf, Lbuf, wo1, bo1, Z, p2s, p2q);
  }
  k_out2 <<<dim3(200), dim3(256), 0, stream>>>(Z, p2s, p2q, go, betao, wo2, bo2, (float*)d_out);
}